// Round 1
// baseline (606.232 us; speedup 1.0000x reference)
//
#include <hip/hip_runtime.h>
#include <hip/hip_bf16.h>
#include <cstddef>

#define TT 50
#define NN 512
#define DIN 3
#define HH 128
#define NHD 4
#define HDIM 32
#define NPG 64
#define SROW 132   // padded LDS row stride (floats) to avoid 128-stride bank conflicts

// ---------------------------------------------------------------------------
// Kernel A: mask, degree, dinv, and compacted neighbor lists (CSC by column j)
// grid: T*4 blocks, 128 threads; block covers j in [jt*128, jt*128+128)
// ---------------------------------------------------------------------------
__global__ __launch_bounds__(128) void mask_deg_kernel(
    const float* __restrict__ adj, const int* __restrict__ ego,
    float* __restrict__ MF, float* __restrict__ DINV,
    int* __restrict__ CNT, unsigned short* __restrict__ IDX)
{
    const int bid = blockIdx.x;
    const int t = bid >> 2;
    const int jt = bid & 3;
    const int tid = threadIdx.x;

    __shared__ float mfS[NN];
    for (int i = tid; i < NN; i += 128) {
        int b = i >> 6, p = i & 63;
        mfS[i] = (ego[b * (TT * NPG) + t * NPG + p] != 0) ? 1.0f : 0.0f;
    }
    __syncthreads();

    const int j = jt * 128 + tid;
    const float mfj = mfS[j];
    MF[t * NN + j] = mfj;

    int cnt = 0;
    if (mfj != 0.0f) {
        float s = 0.0f;
        const size_t abase = (size_t)t * NN * NN + j;
        const size_t lbase = ((size_t)t * NN + j) * NN;
        for (int i = 0; i < NN; ++i) {
            float a = adj[abase + (size_t)i * NN];
            if (a != 0.0f && mfS[i] != 0.0f) {
                IDX[lbase + cnt] = (unsigned short)i;
                ++cnt;
                s += a;
            }
        }
        DINV[t * NN + j] = rsqrtf(s + 1.0f);   // deg = s + 1 (self loop), always > 0
    } else {
        DINV[t * NN + j] = 0.0f;
    }
    CNT[t * NN + j] = cnt;
}

// ---------------------------------------------------------------------------
// Kernel B: XW1[t][i][f] = (x[t][i][:] . W1[:,f]) * dinv[t][i]
// ---------------------------------------------------------------------------
__global__ __launch_bounds__(256) void xw1_kernel(
    const float* __restrict__ x, const float* __restrict__ W1,
    const float* __restrict__ DINV, float* __restrict__ XW)
{
    const int idx = blockIdx.x * 256 + threadIdx.x;   // < T*NN*H exactly
    const int t = idx >> 16;           // NN*H = 65536
    const int r = idx & 65535;
    const int i = r >> 7;
    const int f = r & 127;
    const float* xp = x + ((size_t)t * NN + i) * DIN;
    float v = xp[0] * W1[f] + xp[1] * W1[HH + f] + xp[2] * W1[2 * HH + f];
    XW[idx] = v * DINV[t * NN + i];
}

// ---------------------------------------------------------------------------
// Kernel C: OUT[t][j][f] = relu?( dinv[t][j] * (XW[t][j][f] + sum_list XW[t][i][f]) + b[f] )
// (zero rows for non-ego j). grid: T*NN blocks, 128 threads.
// ---------------------------------------------------------------------------
__global__ __launch_bounds__(128) void agg_kernel(
    const float* __restrict__ XW, const float* __restrict__ MF,
    const float* __restrict__ DINV, const int* __restrict__ CNT,
    const unsigned short* __restrict__ IDX, const float* __restrict__ bias,
    float* __restrict__ OUT, int do_relu)
{
    const int bid = blockIdx.x;
    const int t = bid / NN;
    const int j = bid - t * NN;
    const int f = threadIdx.x;

    __shared__ unsigned short sidx[NN];

    const float mfj = MF[t * NN + j];
    int cnt = 0;
    if (mfj != 0.0f) cnt = CNT[t * NN + j];
    const unsigned short* lst = IDX + ((size_t)t * NN + j) * NN;
    for (int k = f; k < cnt; k += 128) sidx[k] = lst[k];
    __syncthreads();

    float outv = 0.0f;
    if (mfj != 0.0f) {
        const float* base = XW + (size_t)t * NN * HH;
        float acc = base[j * HH + f];
        for (int k = 0; k < cnt; ++k) {
            acc += base[(int)sidx[k] * HH + f];
        }
        outv = DINV[t * NN + j] * acc + bias[f];
        if (do_relu) outv = fmaxf(outv, 0.0f);
    }
    OUT[(size_t)t * NN * HH + j * HH + f] = outv;
}

// ---------------------------------------------------------------------------
// Kernel D: XW2[t][i][f] = (H1[t][i][:] . W2[:,f]) * dinv[t][i]
// grid: T*16 blocks (32 rows each), 128 threads. W2 staged in LDS.
// ---------------------------------------------------------------------------
__global__ __launch_bounds__(128) void xw2_kernel(
    const float* __restrict__ Hin, const float* __restrict__ W2,
    const float* __restrict__ DINV, float* __restrict__ XW2)
{
    const int bid = blockIdx.x;
    const int t = bid >> 4;
    const int chunk = bid & 15;
    const int f = threadIdx.x;

    __shared__ float W2S[HH * HH];   // 64 KB
    __shared__ float rowsS[32 * HH]; // 16 KB

    for (int idx = f; idx < HH * HH; idx += 128) W2S[idx] = W2[idx];
    const float* hb = Hin + (size_t)t * NN * HH + (size_t)chunk * 32 * HH;
    for (int idx = f; idx < 32 * HH; idx += 128) rowsS[idx] = hb[idx];
    __syncthreads();

    float acc[32];
#pragma unroll
    for (int r = 0; r < 32; ++r) acc[r] = 0.0f;

    for (int h = 0; h < HH; ++h) {
        float w = W2S[h * HH + f];
#pragma unroll
        for (int r = 0; r < 32; ++r) acc[r] = fmaf(rowsS[r * HH + h], w, acc[r]);
    }

    float* ob = XW2 + (size_t)t * NN * HH + (size_t)chunk * 32 * HH;
    const float* dv = DINV + t * NN + chunk * 32;
#pragma unroll
    for (int r = 0; r < 32; ++r) ob[r * HH + f] = acc[r] * dv[r];
}

// ---------------------------------------------------------------------------
// Kernel E: fused per-node projections + MHA + out_proj.
// grid: NN blocks, 256 threads (o = tid&127, half = tid>>7 handles 25 t-rows)
// ---------------------------------------------------------------------------
__device__ __forceinline__ void gemm_stage(const float* __restrict__ Sin,
                                           const float* __restrict__ W,
                                           int o, int t0, float acc[25])
{
#pragma unroll
    for (int tt = 0; tt < 25; ++tt) acc[tt] = 0.0f;
    const float4* w4 = reinterpret_cast<const float4*>(W + (size_t)o * HH);
    for (int h4 = 0; h4 < HH / 4; ++h4) {
        float4 w = w4[h4];
#pragma unroll
        for (int tt = 0; tt < 25; ++tt) {
            float4 sv = *reinterpret_cast<const float4*>(&Sin[(t0 + tt) * SROW + h4 * 4]);
            float a = acc[tt];
            a = fmaf(sv.x, w.x, a);
            a = fmaf(sv.y, w.y, a);
            a = fmaf(sv.z, w.z, a);
            a = fmaf(sv.w, w.w, a);
            acc[tt] = a;
        }
    }
}

__global__ __launch_bounds__(256) void node_attn_kernel(
    const float* __restrict__ EMB,
    const float* __restrict__ Wq, const float* __restrict__ bq,
    const float* __restrict__ Wk, const float* __restrict__ bk,
    const float* __restrict__ Wv, const float* __restrict__ bv,
    const float* __restrict__ W_in, const float* __restrict__ b_in,
    const float* __restrict__ W_out, const float* __restrict__ b_out,
    float* __restrict__ out)
{
    __shared__ float S0[TT * SROW];  // emb, later attention output
    __shared__ float Sq[TT * SROW];
    __shared__ float Sk[TT * SROW];
    __shared__ float Sv[TT * SROW];

    const int n = blockIdx.x;
    const int tid = threadIdx.x;
    const int o = tid & 127;
    const int half = tid >> 7;
    const int t0 = half * 25;

    // stage emb_n [50][128]
    for (int idx = tid; idx < TT * HH; idx += 256) {
        int t = idx >> 7, h = idx & 127;
        S0[t * SROW + h] = EMB[(size_t)t * (NN * HH) + (size_t)n * HH + h];
    }
    __syncthreads();

    float acc[25];

    // q = emb @ Wq^T + bq  -> Sq
    gemm_stage(S0, Wq + (size_t)n * HH * HH, o, t0, acc);
    {
        float b = bq[n * HH + o];
#pragma unroll
        for (int tt = 0; tt < 25; ++tt) Sq[(t0 + tt) * SROW + o] = acc[tt] + b;
    }
    // k -> Sk
    gemm_stage(S0, Wk + (size_t)n * HH * HH, o, t0, acc);
    {
        float b = bk[n * HH + o];
#pragma unroll
        for (int tt = 0; tt < 25; ++tt) Sk[(t0 + tt) * SROW + o] = acc[tt] + b;
    }
    // v -> Sv
    gemm_stage(S0, Wv + (size_t)n * HH * HH, o, t0, acc);
    {
        float b = bv[n * HH + o];
#pragma unroll
        for (int tt = 0; tt < 25; ++tt) Sv[(t0 + tt) * SROW + o] = acc[tt] + b;
    }
    __syncthreads();   // qkv visible

    const float scale = 0.17677669529663687f;  // 1/sqrt(32)

    // qh = (q @ WQ^T + bQ) * scale  (in-place Sq)
    gemm_stage(Sq, W_in + (size_t)n * 3 * HH * HH, o, t0, acc);
    __syncthreads();   // all reads of Sq done
    {
        float b = b_in[n * 3 * HH + o];
#pragma unroll
        for (int tt = 0; tt < 25; ++tt) Sq[(t0 + tt) * SROW + o] = (acc[tt] + b) * scale;
    }
    // kh (in-place Sk)
    gemm_stage(Sk, W_in + (size_t)n * 3 * HH * HH + (size_t)HH * HH, o, t0, acc);
    __syncthreads();
    {
        float b = b_in[n * 3 * HH + HH + o];
#pragma unroll
        for (int tt = 0; tt < 25; ++tt) Sk[(t0 + tt) * SROW + o] = acc[tt] + b;
    }
    // vh (in-place Sv)
    gemm_stage(Sv, W_in + (size_t)n * 3 * HH * HH + (size_t)2 * HH * HH, o, t0, acc);
    __syncthreads();
    {
        float b = b_in[n * 3 * HH + 2 * HH + o];
#pragma unroll
        for (int tt = 0; tt < 25; ++tt) Sv[(t0 + tt) * SROW + o] = acc[tt] + b;
    }
    __syncthreads();   // qh/kh/vh visible

    // attention: one (t, head) pair per thread, 200 active
    if (tid < TT * NHD) {
        const int t = tid >> 2;
        const int hd = tid & 3;
        const int qbase = t * SROW + hd * HDIM;
        float s[TT];
        float m = -1e30f;
        for (int j = 0; j < TT; ++j) {
            const int kbase = j * SROW + hd * HDIM;
            float d = 0.0f;
#pragma unroll
            for (int dd = 0; dd < HDIM; dd += 4) {
                float4 qv = *reinterpret_cast<const float4*>(&Sq[qbase + dd]);
                float4 kv = *reinterpret_cast<const float4*>(&Sk[kbase + dd]);
                d = fmaf(qv.x, kv.x, d);
                d = fmaf(qv.y, kv.y, d);
                d = fmaf(qv.z, kv.z, d);
                d = fmaf(qv.w, kv.w, d);
            }
            s[j] = d;
            m = fmaxf(m, d);
        }
        float sum = 0.0f;
        for (int j = 0; j < TT; ++j) {
            float p = __expf(s[j] - m);
            s[j] = p;
            sum += p;
        }
        const float inv = 1.0f / sum;
        for (int dd = 0; dd < HDIM; ++dd) {
            float a = 0.0f;
            for (int j = 0; j < TT; ++j) a = fmaf(s[j], Sv[j * SROW + hd * HDIM + dd], a);
            S0[qbase + dd] = a * inv;
        }
    }
    __syncthreads();   // attention output in S0

    // out = o @ W_out^T + b_out -> global
    gemm_stage(S0, W_out + (size_t)n * HH * HH, o, t0, acc);
    {
        float b = b_out[n * HH + o];
        float* outp = out + (size_t)n * (TT * HH);
#pragma unroll
        for (int tt = 0; tt < 25; ++tt) outp[(t0 + tt) * HH + o] = acc[tt] + b;
    }
}

// ---------------------------------------------------------------------------
extern "C" void kernel_launch(void* const* d_in, const int* in_sizes, int n_in,
                              void* d_out, int out_size, void* d_ws, size_t ws_size,
                              hipStream_t stream)
{
    const float* x     = (const float*)d_in[0];
    const float* adj   = (const float*)d_in[1];
    const int*   ego   = (const int*)d_in[2];
    const float* W1    = (const float*)d_in[3];
    const float* b1    = (const float*)d_in[4];
    const float* W2    = (const float*)d_in[5];
    const float* b2    = (const float*)d_in[6];
    const float* Wq    = (const float*)d_in[7];
    const float* bq    = (const float*)d_in[8];
    const float* Wk    = (const float*)d_in[9];
    const float* bk    = (const float*)d_in[10];
    const float* Wv    = (const float*)d_in[11];
    const float* bv    = (const float*)d_in[12];
    const float* W_in  = (const float*)d_in[13];
    const float* b_in  = (const float*)d_in[14];
    const float* W_out = (const float*)d_in[15];
    const float* b_out = (const float*)d_in[16];
    float* out = (float*)d_out;

    char* ws = (char*)d_ws;
    float*          MF   = (float*)(ws + 0);
    float*          DINV = (float*)(ws + 102400);
    int*            CNT  = (int*)(ws + 204800);
    unsigned short* IDX  = (unsigned short*)(ws + 307200);       // 26,214,400 B
    float*          XW   = (float*)(ws + 26521600);              // 13,107,200 B
    float*          H1   = (float*)(ws + 39628800);              // 13,107,200 B
    float*          EMB  = (float*)(ws + 52736000);              // 13,107,200 B

    mask_deg_kernel<<<dim3(TT * 4), dim3(128), 0, stream>>>(adj, ego, MF, DINV, CNT, IDX);
    xw1_kernel<<<dim3(12800), dim3(256), 0, stream>>>(x, W1, DINV, XW);
    agg_kernel<<<dim3(TT * NN), dim3(128), 0, stream>>>(XW, MF, DINV, CNT, IDX, b1, H1, 1);
    xw2_kernel<<<dim3(TT * 16), dim3(128), 0, stream>>>(H1, W2, DINV, XW);
    agg_kernel<<<dim3(TT * NN), dim3(128), 0, stream>>>(XW, MF, DINV, CNT, IDX, b2, EMB, 0);
    node_attn_kernel<<<dim3(NN), dim3(256), 0, stream>>>(EMB, Wq, bq, Wk, bk, Wv, bv,
                                                         W_in, b_in, W_out, b_out, out);
}

// Round 2
// 406.847 us; speedup vs baseline: 1.4901x; 1.4901x over previous
//
#include <hip/hip_runtime.h>
#include <hip/hip_bf16.h>
#include <cstddef>

#define TT 50
#define NN 512
#define DIN 3
#define HH 128
#define NHD 4
#define NPG 64

typedef short short8 __attribute__((ext_vector_type(8)));
typedef float f32x4 __attribute__((ext_vector_type(4)));

// ---- fused attention LDS layout (ushort elems) ----
#define SROW 136   // stage buffer row stride (bf16) : 272B = 68dw == 4 mod 32 -> 2-way free, 16B aligned rows
#define VROW 56    // Svt row stride: 112B = 28dw, 8 bank-groups, rows 16B aligned
#define PROW 72    // Pq row stride: 144B = 36dw == 4 mod 32 -> 2-way free, 16B aligned
#define SQ_OFF 0
#define SK_OFF 6800
#define SV_OFF 13600          // 7184 elems (128*56 + 16 tail pad)
#define PQ_OFF 20784          // 4 heads * 64*72 = 18432 (emb staged here first)
#define SMEM_ELEMS 39216      // 78,432 B -> 2 blocks/CU

static __device__ __forceinline__ unsigned short f2b(float f) {
    unsigned int u = __builtin_bit_cast(unsigned int, f);
    unsigned int r = (u + 0x7fffu + ((u >> 16) & 1u)) >> 16;
    return (unsigned short)r;
}

// ---------------------------------------------------------------------------
// Kernel A: mask, degree, dinv, and compacted neighbor lists (CSC by column j)
// ---------------------------------------------------------------------------
__global__ __launch_bounds__(128) void mask_deg_kernel(
    const float* __restrict__ adj, const int* __restrict__ ego,
    float* __restrict__ MF, float* __restrict__ DINV,
    int* __restrict__ CNT, unsigned short* __restrict__ IDX)
{
    const int bid = blockIdx.x;
    const int t = bid >> 2;
    const int jt = bid & 3;
    const int tid = threadIdx.x;

    __shared__ float mfS[NN];
    for (int i = tid; i < NN; i += 128) {
        int b = i >> 6, p = i & 63;
        mfS[i] = (ego[b * (TT * NPG) + t * NPG + p] != 0) ? 1.0f : 0.0f;
    }
    __syncthreads();

    const int j = jt * 128 + tid;
    const float mfj = mfS[j];
    MF[t * NN + j] = mfj;

    int cnt = 0;
    if (mfj != 0.0f) {
        float s = 0.0f;
        const size_t abase = (size_t)t * NN * NN + j;
        const size_t lbase = ((size_t)t * NN + j) * NN;
        for (int i = 0; i < NN; ++i) {
            float a = adj[abase + (size_t)i * NN];
            if (a != 0.0f && mfS[i] != 0.0f) {
                IDX[lbase + cnt] = (unsigned short)i;
                ++cnt;
                s += a;
            }
        }
        DINV[t * NN + j] = rsqrtf(s + 1.0f);
    } else {
        DINV[t * NN + j] = 0.0f;
    }
    CNT[t * NN + j] = cnt;
}

// ---------------------------------------------------------------------------
// Kernel B: XW1 = (x @ W1) * dinv
// ---------------------------------------------------------------------------
__global__ __launch_bounds__(256) void xw1_kernel(
    const float* __restrict__ x, const float* __restrict__ W1,
    const float* __restrict__ DINV, float* __restrict__ XW)
{
    const int idx = blockIdx.x * 256 + threadIdx.x;
    const int t = idx >> 16;
    const int r = idx & 65535;
    const int i = r >> 7;
    const int f = r & 127;
    const float* xp = x + ((size_t)t * NN + i) * DIN;
    float v = xp[0] * W1[f] + xp[1] * W1[HH + f] + xp[2] * W1[2 * HH + f];
    XW[idx] = v * DINV[t * NN + i];
}

// ---------------------------------------------------------------------------
// Kernel C: column aggregation via neighbor lists + bias (+ReLU)
// ---------------------------------------------------------------------------
__global__ __launch_bounds__(128) void agg_kernel(
    const float* __restrict__ XW, const float* __restrict__ MF,
    const float* __restrict__ DINV, const int* __restrict__ CNT,
    const unsigned short* __restrict__ IDX, const float* __restrict__ bias,
    float* __restrict__ OUT, int do_relu)
{
    const int bid = blockIdx.x;
    const int t = bid / NN;
    const int j = bid - t * NN;
    const int f = threadIdx.x;

    __shared__ unsigned short sidx[NN];

    const float mfj = MF[t * NN + j];
    int cnt = 0;
    if (mfj != 0.0f) cnt = CNT[t * NN + j];
    const unsigned short* lst = IDX + ((size_t)t * NN + j) * NN;
    for (int k = f; k < cnt; k += 128) sidx[k] = lst[k];
    __syncthreads();

    float outv = 0.0f;
    if (mfj != 0.0f) {
        const float* base = XW + (size_t)t * NN * HH;
        float acc = base[j * HH + f];
        for (int k = 0; k < cnt; ++k) {
            acc += base[(int)sidx[k] * HH + f];
        }
        outv = DINV[t * NN + j] * acc + bias[f];
        if (do_relu) outv = fmaxf(outv, 0.0f);
    }
    OUT[(size_t)t * NN * HH + j * HH + f] = outv;
}

// ---------------------------------------------------------------------------
// Kernel D: XW2 = (H1 @ W2) * dinv, W2 staged in LDS
// ---------------------------------------------------------------------------
__global__ __launch_bounds__(128) void xw2_kernel(
    const float* __restrict__ Hin, const float* __restrict__ W2,
    const float* __restrict__ DINV, float* __restrict__ XW2)
{
    const int bid = blockIdx.x;
    const int t = bid >> 4;
    const int chunk = bid & 15;
    const int f = threadIdx.x;

    __shared__ float W2S[HH * HH];
    __shared__ float rowsS[32 * HH];

    for (int idx = f; idx < HH * HH; idx += 128) W2S[idx] = W2[idx];
    const float* hb = Hin + (size_t)t * NN * HH + (size_t)chunk * 32 * HH;
    for (int idx = f; idx < 32 * HH; idx += 128) rowsS[idx] = hb[idx];
    __syncthreads();

    float acc[32];
#pragma unroll
    for (int r = 0; r < 32; ++r) acc[r] = 0.0f;

    for (int h = 0; h < HH; ++h) {
        float w = W2S[h * HH + f];
#pragma unroll
        for (int r = 0; r < 32; ++r) acc[r] = fmaf(rowsS[r * HH + h], w, acc[r]);
    }

    float* ob = XW2 + (size_t)t * NN * HH + (size_t)chunk * 32 * HH;
    const float* dv = DINV + t * NN + chunk * 32;
#pragma unroll
    for (int r = 0; r < 32; ++r) ob[r * HH + f] = acc[r] * dv[r];
}

// ---------------------------------------------------------------------------
// Kernel E (MFMA): fused per-node projections + MHA + out_proj.
// 1 block = 1 node, 4 waves. Wave w owns output cols [32w, 32w+32) in stage
// GEMMs, and head w in attention.
// Fragment layout (16x16x32 bf16): A row = lane&15, k = 8*(lane>>4)+i (contig,
// ds_read_b128); B col = lane&15, same k; D row = 4*(lane>>4)+reg, col=lane&15.
// ---------------------------------------------------------------------------
// MODE: 0 = store LDS (stride SROW); 1 = same + *1/sqrt(32); 2 = transposed
//       store to Svt (stride VROW); 3 = store fp32 to global
template<int MODE>
__device__ __forceinline__ void stage_gemm(
    unsigned short* __restrict__ sm, int in_off, int out_off,
    const float* __restrict__ W, const float* __restrict__ bias,
    float* __restrict__ gout)
{
    const int tid = threadIdx.x;
    const int lane = tid & 63;
    const int wid = tid >> 6;
    const int g = lane >> 4, c = lane & 15;
    const int nt0 = 2 * wid;

    short8 bf[2][4];
    float bv[2];
#pragma unroll
    for (int i = 0; i < 2; ++i) {
        const int o = 16 * (nt0 + i) + c;
        const float* wr = W + o * HH + 8 * g;
        bv[i] = bias[o];
#pragma unroll
        for (int kb = 0; kb < 4; ++kb) {
            float4 w0 = *reinterpret_cast<const float4*>(wr + kb * 32);
            float4 w1 = *reinterpret_cast<const float4*>(wr + kb * 32 + 4);
            short8 tt;
            tt[0] = (short)f2b(w0.x); tt[1] = (short)f2b(w0.y);
            tt[2] = (short)f2b(w0.z); tt[3] = (short)f2b(w0.w);
            tt[4] = (short)f2b(w1.x); tt[5] = (short)f2b(w1.y);
            tt[6] = (short)f2b(w1.z); tt[7] = (short)f2b(w1.w);
            bf[i][kb] = tt;
        }
    }

    f32x4 acc[4][2];
#pragma unroll
    for (int m = 0; m < 4; ++m)
#pragma unroll
        for (int i = 0; i < 2; ++i)
            acc[m][i] = (f32x4)(0.0f);

#pragma unroll
    for (int kb = 0; kb < 4; ++kb) {
        short8 af[4];
#pragma unroll
        for (int m = 0; m < 4; ++m)
            af[m] = *reinterpret_cast<const short8*>(&sm[in_off + (16 * m + c) * SROW + kb * 32 + 8 * g]);
#pragma unroll
        for (int m = 0; m < 4; ++m)
#pragma unroll
            for (int i = 0; i < 2; ++i)
                acc[m][i] = __builtin_amdgcn_mfma_f32_16x16x32_bf16(af[m], bf[i][kb], acc[m][i], 0, 0, 0);
    }
    __syncthreads();   // all reads of in_off done (in-place safe)

    constexpr float scale = 0.17677669529663687f;  // 1/sqrt(32)
#pragma unroll
    for (int m = 0; m < 4; ++m)
#pragma unroll
        for (int i = 0; i < 2; ++i)
#pragma unroll
            for (int r = 0; r < 4; ++r) {
                const int row = 16 * m + 4 * g + r;
                if (row >= TT) continue;   // compile-time true for m<3
                float v = acc[m][i][r] + bv[i];
                if (MODE == 1) v *= scale;
                const int col = 16 * (nt0 + i) + c;
                if (MODE == 3)      gout[row * HH + col] = v;
                else if (MODE == 2) sm[out_off + col * VROW + row] = f2b(v);
                else                sm[out_off + row * SROW + col] = f2b(v);
            }
    __syncthreads();
}

__global__ __launch_bounds__(256, 2) void node_attn_kernel(
    const float* __restrict__ EMB,
    const float* __restrict__ Wq, const float* __restrict__ bq,
    const float* __restrict__ Wk, const float* __restrict__ bk,
    const float* __restrict__ Wv, const float* __restrict__ bv,
    const float* __restrict__ W_in, const float* __restrict__ b_in,
    const float* __restrict__ W_out, const float* __restrict__ b_out,
    float* __restrict__ out)
{
    __shared__ unsigned short sm[SMEM_ELEMS];
    const int n = blockIdx.x;
    const int tid = threadIdx.x;
    const int lane = tid & 63;
    const int wid = tid >> 6;
    const int g = lane >> 4, c = lane & 15;

    // zero Svt tail pad (cols 50..55 get overwritten by Sv staging -> they end
    // finite; the 16-elem tail past row 127 must be finite too)
    for (int idx = tid; idx < HH * 6 + 16; idx += 256) {
        if (idx < HH * 6) {
            int d = idx / 6, cc = idx - d * 6;
            sm[SV_OFF + d * VROW + TT + cc] = 0;
        } else {
            sm[SV_OFF + HH * VROW + (idx - HH * 6)] = 0;
        }
    }

    // stage emb (bf16) into PQ region, stride SROW
    for (int idx = tid; idx < TT * (HH / 4); idx += 256) {
        int t = idx >> 5;
        int h4 = (idx & 31) * 4;
        float4 v = *reinterpret_cast<const float4*>(&EMB[((size_t)t * NN + n) * HH + h4]);
        unsigned short* p = &sm[PQ_OFF + t * SROW + h4];
        p[0] = f2b(v.x); p[1] = f2b(v.y); p[2] = f2b(v.z); p[3] = f2b(v.w);
    }
    __syncthreads();

    const size_t nHH = (size_t)n * HH * HH;
    const size_t n3HH = (size_t)n * 3 * HH * HH;

    // q/k/v projections (read emb @ PQ region)
    stage_gemm<0>(sm, PQ_OFF, SQ_OFF, Wq + nHH, bq + (size_t)n * HH, nullptr);
    stage_gemm<0>(sm, PQ_OFF, SK_OFF, Wk + nHH, bk + (size_t)n * HH, nullptr);
    stage_gemm<0>(sm, PQ_OFF, SV_OFF, Wv + nHH, bv + (size_t)n * HH, nullptr);
    // in_proj: qh (scaled, in-place), kh (in-place), vh (transposed -> Svt)
    stage_gemm<1>(sm, SQ_OFF, SQ_OFF, W_in + n3HH,                 b_in + (size_t)n * 3 * HH,          nullptr);
    stage_gemm<0>(sm, SK_OFF, SK_OFF, W_in + n3HH + HH * HH,       b_in + (size_t)n * 3 * HH + HH,     nullptr);
    stage_gemm<2>(sm, SV_OFF, SV_OFF, W_in + n3HH + 2 * HH * HH,   b_in + (size_t)n * 3 * HH + 2 * HH, nullptr);

    // ---- attention: wave = head ----
    const int hd = wid;

    // QK^T: S[q][j] = sum_d qh[q][d] kh[j][d], K=32 -> one MFMA per tile
    f32x4 sacc[4][4];
#pragma unroll
    for (int m = 0; m < 4; ++m)
#pragma unroll
        for (int j = 0; j < 4; ++j) sacc[m][j] = (f32x4)(0.0f);

    short8 aq[4], bk8[4];
#pragma unroll
    for (int m = 0; m < 4; ++m)
        aq[m] = *reinterpret_cast<const short8*>(&sm[SQ_OFF + (16 * m + c) * SROW + hd * 32 + 8 * g]);
#pragma unroll
    for (int j = 0; j < 4; ++j)
        bk8[j] = *reinterpret_cast<const short8*>(&sm[SK_OFF + (16 * j + c) * SROW + hd * 32 + 8 * g]);
#pragma unroll
    for (int m = 0; m < 4; ++m)
#pragma unroll
        for (int j = 0; j < 4; ++j)
            sacc[m][j] = __builtin_amdgcn_mfma_f32_16x16x32_bf16(aq[m], bk8[j], sacc[m][j], 0, 0, 0);

    // softmax over j (cols: j = 16*nt + c across 16 lanes), normalized P -> Pq LDS
    const bool mask3 = (c >= 2);   // nt==3: j = 48+c >= 50
    unsigned short* Pbase = &sm[PQ_OFF + hd * 64 * PROW];
#pragma unroll
    for (int m = 0; m < 4; ++m)
#pragma unroll
        for (int r = 0; r < 4; ++r) {
            float v0 = sacc[m][0][r], v1 = sacc[m][1][r], v2 = sacc[m][2][r];
            float v3 = mask3 ? -3.0e38f : sacc[m][3][r];
            float mx = fmaxf(fmaxf(v0, v1), fmaxf(v2, v3));
            mx = fmaxf(mx, __shfl_xor(mx, 1, 16));
            mx = fmaxf(mx, __shfl_xor(mx, 2, 16));
            mx = fmaxf(mx, __shfl_xor(mx, 4, 16));
            mx = fmaxf(mx, __shfl_xor(mx, 8, 16));
            float e0 = __expf(v0 - mx), e1 = __expf(v1 - mx), e2 = __expf(v2 - mx);
            float e3 = mask3 ? 0.0f : __expf(v3 - mx);
            float sum_ = e0 + e1 + e2 + e3;
            sum_ += __shfl_xor(sum_, 1, 16);
            sum_ += __shfl_xor(sum_, 2, 16);
            sum_ += __shfl_xor(sum_, 4, 16);
            sum_ += __shfl_xor(sum_, 8, 16);
            float inv = 1.0f / sum_;
            const int q = 16 * m + 4 * g + r;
            unsigned short* pr = Pbase + q * PROW;
            pr[c]      = f2b(e0 * inv);
            pr[16 + c] = f2b(e1 * inv);
            pr[32 + c] = f2b(e2 * inv);
            pr[48 + c] = f2b(e3 * inv);
        }
    __syncthreads();   // Pq visible; also: all QK^T reads of SQ done

    // PV: O^T[d][q] = sum_j vh^T[d][j] P[q][j]; A from Svt, B from Pq
    f32x4 pacc[2][4];
#pragma unroll
    for (int mtd = 0; mtd < 2; ++mtd)
#pragma unroll
        for (int ntq = 0; ntq < 4; ++ntq) pacc[mtd][ntq] = (f32x4)(0.0f);

#pragma unroll
    for (int kb = 0; kb < 2; ++kb) {
        short8 av[2], bp[4];
#pragma unroll
        for (int mtd = 0; mtd < 2; ++mtd)
            av[mtd] = *reinterpret_cast<const short8*>(&sm[SV_OFF + (hd * 32 + 16 * mtd + c) * VROW + kb * 32 + 8 * g]);
#pragma unroll
        for (int ntq = 0; ntq < 4; ++ntq)
            bp[ntq] = *reinterpret_cast<const short8*>(&sm[PQ_OFF + hd * 64 * PROW + (16 * ntq + c) * PROW + kb * 32 + 8 * g]);
#pragma unroll
        for (int mtd = 0; mtd < 2; ++mtd)
#pragma unroll
            for (int ntq = 0; ntq < 4; ++ntq)
                pacc[mtd][ntq] = __builtin_amdgcn_mfma_f32_16x16x32_bf16(av[mtd], bp[ntq], pacc[mtd][ntq], 0, 0, 0);
    }

    // store attention output transposed into So (= SQ region, dead)
#pragma unroll
    for (int mtd = 0; mtd < 2; ++mtd)
#pragma unroll
        for (int ntq = 0; ntq < 4; ++ntq)
#pragma unroll
            for (int r = 0; r < 4; ++r) {
                const int q = 16 * ntq + c;
                if (q < TT)
                    sm[SQ_OFF + q * SROW + hd * 32 + 16 * mtd + 4 * g + r] = f2b(pacc[mtd][ntq][r]);
            }
    __syncthreads();

    // out_proj -> global fp32
    stage_gemm<3>(sm, SQ_OFF, 0, W_out + nHH, b_out + (size_t)n * HH, out + (size_t)n * TT * HH);
}

// ---------------------------------------------------------------------------
extern "C" void kernel_launch(void* const* d_in, const int* in_sizes, int n_in,
                              void* d_out, int out_size, void* d_ws, size_t ws_size,
                              hipStream_t stream)
{
    const float* x     = (const float*)d_in[0];
    const float* adj   = (const float*)d_in[1];
    const int*   ego   = (const int*)d_in[2];
    const float* W1    = (const float*)d_in[3];
    const float* b1    = (const float*)d_in[4];
    const float* W2    = (const float*)d_in[5];
    const float* b2    = (const float*)d_in[6];
    const float* Wq    = (const float*)d_in[7];
    const float* bq    = (const float*)d_in[8];
    const float* Wk    = (const float*)d_in[9];
    const float* bk    = (const float*)d_in[10];
    const float* Wv    = (const float*)d_in[11];
    const float* bv    = (const float*)d_in[12];
    const float* W_in  = (const float*)d_in[13];
    const float* b_in  = (const float*)d_in[14];
    const float* W_out = (const float*)d_in[15];
    const float* b_out = (const float*)d_in[16];
    float* out = (float*)d_out;

    char* ws = (char*)d_ws;
    float*          MF   = (float*)(ws + 0);
    float*          DINV = (float*)(ws + 102400);
    int*            CNT  = (int*)(ws + 204800);
    unsigned short* IDX  = (unsigned short*)(ws + 307200);       // 26,214,400 B
    float*          XW   = (float*)(ws + 26521600);              // 13,107,200 B
    float*          H1   = (float*)(ws + 39628800);              // 13,107,200 B
    float*          EMB  = (float*)(ws + 52736000);              // 13,107,200 B

    mask_deg_kernel<<<dim3(TT * 4), dim3(128), 0, stream>>>(adj, ego, MF, DINV, CNT, IDX);
    xw1_kernel<<<dim3(12800), dim3(256), 0, stream>>>(x, W1, DINV, XW);
    agg_kernel<<<dim3(TT * NN), dim3(128), 0, stream>>>(XW, MF, DINV, CNT, IDX, b1, H1, 1);
    xw2_kernel<<<dim3(TT * 16), dim3(128), 0, stream>>>(H1, W2, DINV, XW);
    agg_kernel<<<dim3(TT * NN), dim3(128), 0, stream>>>(XW, MF, DINV, CNT, IDX, b2, EMB, 0);
    node_attn_kernel<<<dim3(NN), dim3(256), 0, stream>>>(EMB, Wq, bq, Wk, bk, Wv, bv,
                                                         W_in, b_in, W_out, b_out, out);
}

// Round 3
// 224.845 us; speedup vs baseline: 2.6962x; 1.8095x over previous
//
#include <hip/hip_runtime.h>
#include <hip/hip_bf16.h>
#include <cstddef>

#define TT 50
#define NN 512
#define DIN 3
#define HH 128
#define NHD 4
#define NPG 64

typedef short short8 __attribute__((ext_vector_type(8)));
typedef float f32x4 __attribute__((ext_vector_type(4)));

// ---- fused attention LDS layout (ushort elems) ----
#define SROW 136   // stage buffer row stride (bf16)
#define VROW 56    // Svt row stride
#define PROW 72    // Pq row stride
#define SQ_OFF 0
#define SK_OFF 6800
#define SV_OFF 13600
#define PQ_OFF 20784
#define SMEM_ELEMS 39216      // 78,432 B -> 2 blocks/CU

static __device__ __forceinline__ unsigned short f2b(float f) {
    unsigned int u = __builtin_bit_cast(unsigned int, f);
    unsigned int r = (u + 0x7fffu + ((u >> 16) & 1u)) >> 16;
    return (unsigned short)r;
}

// ---------------------------------------------------------------------------
// Kernel A0: ego mask -> MF [T][NN]
// ---------------------------------------------------------------------------
__global__ __launch_bounds__(256) void mf_kernel(
    const int* __restrict__ ego, float* __restrict__ MF)
{
    const int idx = blockIdx.x * 256 + threadIdx.x;   // < T*NN
    const int t = idx >> 9;
    const int i = idx & 511;
    const int b = i >> 6, p = i & 63;
    MF[idx] = (ego[b * (TT * NPG) + t * NPG + p] != 0) ? 1.0f : 0.0f;
}

// ---------------------------------------------------------------------------
// Kernel A2: edge extraction by coalesced ROW scan + atomic scatter into
// per-column lists. block = one (t,i) row, 128 threads (float4 each).
// Requires CNT zeroed. Order within a list is arbitrary (sum is commutative).
// Adjacency values are exactly 0/1 per the reference generator.
// ---------------------------------------------------------------------------
__global__ __launch_bounds__(128) void edge_kernel(
    const float* __restrict__ adj, const float* __restrict__ MF,
    int* __restrict__ CNT, unsigned short* __restrict__ IDX)
{
    const int bid = blockIdx.x;        // t*NN + i
    const int t = bid >> 9;
    const int i = bid & 511;
    const int tid = threadIdx.x;

    if (MF[t * NN + i] == 0.0f) return;   // uniform across block

    __shared__ float mfS[NN];
    for (int j = tid; j < NN; j += 128) mfS[j] = MF[t * NN + j];
    __syncthreads();

    const float4 a4 = *reinterpret_cast<const float4*>(
        &adj[(size_t)t * NN * NN + (size_t)i * NN + tid * 4]);
    const float av[4] = {a4.x, a4.y, a4.z, a4.w};
    const int jbase = tid * 4;
#pragma unroll
    for (int u = 0; u < 4; ++u) {
        const int j = jbase + u;
        if (av[u] != 0.0f && mfS[j] != 0.0f) {
            int pos = atomicAdd(&CNT[t * NN + j], 1);
            IDX[((size_t)t * NN + j) * NN + pos] = (unsigned short)i;
        }
    }
}

// ---------------------------------------------------------------------------
// Kernel A3: DINV = mf ? rsqrt(cnt+1) : 0
// ---------------------------------------------------------------------------
__global__ __launch_bounds__(256) void dinv_kernel(
    const float* __restrict__ MF, const int* __restrict__ CNT,
    float* __restrict__ DINV)
{
    const int idx = blockIdx.x * 256 + threadIdx.x;   // < T*NN
    DINV[idx] = (MF[idx] != 0.0f) ? rsqrtf((float)CNT[idx] + 1.0f) : 0.0f;
}

// ---------------------------------------------------------------------------
// Kernel B: XW1 = (x @ W1) * dinv
// ---------------------------------------------------------------------------
__global__ __launch_bounds__(256) void xw1_kernel(
    const float* __restrict__ x, const float* __restrict__ W1,
    const float* __restrict__ DINV, float* __restrict__ XW)
{
    const int idx = blockIdx.x * 256 + threadIdx.x;
    const int t = idx >> 16;
    const int r = idx & 65535;
    const int i = r >> 7;
    const int f = r & 127;
    const float* xp = x + ((size_t)t * NN + i) * DIN;
    float v = xp[0] * W1[f] + xp[1] * W1[HH + f] + xp[2] * W1[2 * HH + f];
    XW[idx] = v * DINV[t * NN + i];
}

// ---------------------------------------------------------------------------
// Kernel C: column aggregation via neighbor lists + bias (+ReLU)
// ---------------------------------------------------------------------------
__global__ __launch_bounds__(128) void agg_kernel(
    const float* __restrict__ XW, const float* __restrict__ MF,
    const float* __restrict__ DINV, const int* __restrict__ CNT,
    const unsigned short* __restrict__ IDX, const float* __restrict__ bias,
    float* __restrict__ OUT, int do_relu)
{
    const int bid = blockIdx.x;
    const int t = bid / NN;
    const int j = bid - t * NN;
    const int f = threadIdx.x;

    __shared__ unsigned short sidx[NN];

    const float mfj = MF[t * NN + j];
    int cnt = 0;
    if (mfj != 0.0f) cnt = CNT[t * NN + j];
    const unsigned short* lst = IDX + ((size_t)t * NN + j) * NN;
    for (int k = f; k < cnt; k += 128) sidx[k] = lst[k];
    __syncthreads();

    float outv = 0.0f;
    if (mfj != 0.0f) {
        const float* base = XW + (size_t)t * NN * HH;
        float acc = base[j * HH + f];
        for (int k = 0; k < cnt; ++k) {
            acc += base[(int)sidx[k] * HH + f];
        }
        outv = DINV[t * NN + j] * acc + bias[f];
        if (do_relu) outv = fmaxf(outv, 0.0f);
    }
    OUT[(size_t)t * NN * HH + j * HH + f] = outv;
}

// ---------------------------------------------------------------------------
// Kernel D: XW2 = (H1 @ W2) * dinv, W2 staged in LDS
// ---------------------------------------------------------------------------
__global__ __launch_bounds__(128) void xw2_kernel(
    const float* __restrict__ Hin, const float* __restrict__ W2,
    const float* __restrict__ DINV, float* __restrict__ XW2)
{
    const int bid = blockIdx.x;
    const int t = bid >> 4;
    const int chunk = bid & 15;
    const int f = threadIdx.x;

    __shared__ float W2S[HH * HH];
    __shared__ float rowsS[32 * HH];

    for (int idx = f; idx < HH * HH; idx += 128) W2S[idx] = W2[idx];
    const float* hb = Hin + (size_t)t * NN * HH + (size_t)chunk * 32 * HH;
    for (int idx = f; idx < 32 * HH; idx += 128) rowsS[idx] = hb[idx];
    __syncthreads();

    float acc[32];
#pragma unroll
    for (int r = 0; r < 32; ++r) acc[r] = 0.0f;

    for (int h = 0; h < HH; ++h) {
        float w = W2S[h * HH + f];
#pragma unroll
        for (int r = 0; r < 32; ++r) acc[r] = fmaf(rowsS[r * HH + h], w, acc[r]);
    }

    float* ob = XW2 + (size_t)t * NN * HH + (size_t)chunk * 32 * HH;
    const float* dv = DINV + t * NN + chunk * 32;
#pragma unroll
    for (int r = 0; r < 32; ++r) ob[r * HH + f] = acc[r] * dv[r];
}

// ---------------------------------------------------------------------------
// Kernel E (MFMA): fused per-node projections + MHA + out_proj.
// ---------------------------------------------------------------------------
template<int MODE>
__device__ __forceinline__ void stage_gemm(
    unsigned short* __restrict__ sm, int in_off, int out_off,
    const float* __restrict__ W, const float* __restrict__ bias,
    float* __restrict__ gout)
{
    const int tid = threadIdx.x;
    const int lane = tid & 63;
    const int wid = tid >> 6;
    const int g = lane >> 4, c = lane & 15;
    const int nt0 = 2 * wid;

    short8 bf[2][4];
    float bv[2];
#pragma unroll
    for (int i = 0; i < 2; ++i) {
        const int o = 16 * (nt0 + i) + c;
        const float* wr = W + o * HH + 8 * g;
        bv[i] = bias[o];
#pragma unroll
        for (int kb = 0; kb < 4; ++kb) {
            float4 w0 = *reinterpret_cast<const float4*>(wr + kb * 32);
            float4 w1 = *reinterpret_cast<const float4*>(wr + kb * 32 + 4);
            short8 tt;
            tt[0] = (short)f2b(w0.x); tt[1] = (short)f2b(w0.y);
            tt[2] = (short)f2b(w0.z); tt[3] = (short)f2b(w0.w);
            tt[4] = (short)f2b(w1.x); tt[5] = (short)f2b(w1.y);
            tt[6] = (short)f2b(w1.z); tt[7] = (short)f2b(w1.w);
            bf[i][kb] = tt;
        }
    }

    f32x4 acc[4][2];
#pragma unroll
    for (int m = 0; m < 4; ++m)
#pragma unroll
        for (int i = 0; i < 2; ++i)
            acc[m][i] = (f32x4)(0.0f);

#pragma unroll
    for (int kb = 0; kb < 4; ++kb) {
        short8 af[4];
#pragma unroll
        for (int m = 0; m < 4; ++m)
            af[m] = *reinterpret_cast<const short8*>(&sm[in_off + (16 * m + c) * SROW + kb * 32 + 8 * g]);
#pragma unroll
        for (int m = 0; m < 4; ++m)
#pragma unroll
            for (int i = 0; i < 2; ++i)
                acc[m][i] = __builtin_amdgcn_mfma_f32_16x16x32_bf16(af[m], bf[i][kb], acc[m][i], 0, 0, 0);
    }
    __syncthreads();   // all reads of in_off done (in-place safe)

    constexpr float scale = 0.17677669529663687f;  // 1/sqrt(32)
#pragma unroll
    for (int m = 0; m < 4; ++m)
#pragma unroll
        for (int i = 0; i < 2; ++i)
#pragma unroll
            for (int r = 0; r < 4; ++r) {
                const int row = 16 * m + 4 * g + r;
                if (row >= TT) continue;
                float v = acc[m][i][r] + bv[i];
                if (MODE == 1) v *= scale;
                const int col = 16 * (nt0 + i) + c;
                if (MODE == 3)      gout[row * HH + col] = v;
                else if (MODE == 2) sm[out_off + col * VROW + row] = f2b(v);
                else                sm[out_off + row * SROW + col] = f2b(v);
            }
    __syncthreads();
}

__global__ __launch_bounds__(256, 2) void node_attn_kernel(
    const float* __restrict__ EMB,
    const float* __restrict__ Wq, const float* __restrict__ bq,
    const float* __restrict__ Wk, const float* __restrict__ bk,
    const float* __restrict__ Wv, const float* __restrict__ bv,
    const float* __restrict__ W_in, const float* __restrict__ b_in,
    const float* __restrict__ W_out, const float* __restrict__ b_out,
    float* __restrict__ out)
{
    __shared__ unsigned short sm[SMEM_ELEMS];
    const int n = blockIdx.x;
    const int tid = threadIdx.x;
    const int lane = tid & 63;
    const int wid = tid >> 6;
    const int g = lane >> 4, c = lane & 15;

    for (int idx = tid; idx < HH * 6 + 16; idx += 256) {
        if (idx < HH * 6) {
            int d = idx / 6, cc = idx - d * 6;
            sm[SV_OFF + d * VROW + TT + cc] = 0;
        } else {
            sm[SV_OFF + HH * VROW + (idx - HH * 6)] = 0;
        }
    }

    for (int idx = tid; idx < TT * (HH / 4); idx += 256) {
        int t = idx >> 5;
        int h4 = (idx & 31) * 4;
        float4 v = *reinterpret_cast<const float4*>(&EMB[((size_t)t * NN + n) * HH + h4]);
        unsigned short* p = &sm[PQ_OFF + t * SROW + h4];
        p[0] = f2b(v.x); p[1] = f2b(v.y); p[2] = f2b(v.z); p[3] = f2b(v.w);
    }
    __syncthreads();

    const size_t nHH = (size_t)n * HH * HH;
    const size_t n3HH = (size_t)n * 3 * HH * HH;

    stage_gemm<0>(sm, PQ_OFF, SQ_OFF, Wq + nHH, bq + (size_t)n * HH, nullptr);
    stage_gemm<0>(sm, PQ_OFF, SK_OFF, Wk + nHH, bk + (size_t)n * HH, nullptr);
    stage_gemm<0>(sm, PQ_OFF, SV_OFF, Wv + nHH, bv + (size_t)n * HH, nullptr);
    stage_gemm<1>(sm, SQ_OFF, SQ_OFF, W_in + n3HH,                 b_in + (size_t)n * 3 * HH,          nullptr);
    stage_gemm<0>(sm, SK_OFF, SK_OFF, W_in + n3HH + HH * HH,       b_in + (size_t)n * 3 * HH + HH,     nullptr);
    stage_gemm<2>(sm, SV_OFF, SV_OFF, W_in + n3HH + 2 * HH * HH,   b_in + (size_t)n * 3 * HH + 2 * HH, nullptr);

    const int hd = wid;

    f32x4 sacc[4][4];
#pragma unroll
    for (int m = 0; m < 4; ++m)
#pragma unroll
        for (int j = 0; j < 4; ++j) sacc[m][j] = (f32x4)(0.0f);

    short8 aq[4], bk8[4];
#pragma unroll
    for (int m = 0; m < 4; ++m)
        aq[m] = *reinterpret_cast<const short8*>(&sm[SQ_OFF + (16 * m + c) * SROW + hd * 32 + 8 * g]);
#pragma unroll
    for (int j = 0; j < 4; ++j)
        bk8[j] = *reinterpret_cast<const short8*>(&sm[SK_OFF + (16 * j + c) * SROW + hd * 32 + 8 * g]);
#pragma unroll
    for (int m = 0; m < 4; ++m)
#pragma unroll
        for (int j = 0; j < 4; ++j)
            sacc[m][j] = __builtin_amdgcn_mfma_f32_16x16x32_bf16(aq[m], bk8[j], sacc[m][j], 0, 0, 0);

    const bool mask3 = (c >= 2);
    unsigned short* Pbase = &sm[PQ_OFF + hd * 64 * PROW];
#pragma unroll
    for (int m = 0; m < 4; ++m)
#pragma unroll
        for (int r = 0; r < 4; ++r) {
            float v0 = sacc[m][0][r], v1 = sacc[m][1][r], v2 = sacc[m][2][r];
            float v3 = mask3 ? -3.0e38f : sacc[m][3][r];
            float mx = fmaxf(fmaxf(v0, v1), fmaxf(v2, v3));
            mx = fmaxf(mx, __shfl_xor(mx, 1, 16));
            mx = fmaxf(mx, __shfl_xor(mx, 2, 16));
            mx = fmaxf(mx, __shfl_xor(mx, 4, 16));
            mx = fmaxf(mx, __shfl_xor(mx, 8, 16));
            float e0 = __expf(v0 - mx), e1 = __expf(v1 - mx), e2 = __expf(v2 - mx);
            float e3 = mask3 ? 0.0f : __expf(v3 - mx);
            float sum_ = e0 + e1 + e2 + e3;
            sum_ += __shfl_xor(sum_, 1, 16);
            sum_ += __shfl_xor(sum_, 2, 16);
            sum_ += __shfl_xor(sum_, 4, 16);
            sum_ += __shfl_xor(sum_, 8, 16);
            float inv = 1.0f / sum_;
            const int q = 16 * m + 4 * g + r;
            unsigned short* pr = Pbase + q * PROW;
            pr[c]      = f2b(e0 * inv);
            pr[16 + c] = f2b(e1 * inv);
            pr[32 + c] = f2b(e2 * inv);
            pr[48 + c] = f2b(e3 * inv);
        }
    __syncthreads();

    f32x4 pacc[2][4];
#pragma unroll
    for (int mtd = 0; mtd < 2; ++mtd)
#pragma unroll
        for (int ntq = 0; ntq < 4; ++ntq) pacc[mtd][ntq] = (f32x4)(0.0f);

#pragma unroll
    for (int kb = 0; kb < 2; ++kb) {
        short8 av[2], bp[4];
#pragma unroll
        for (int mtd = 0; mtd < 2; ++mtd)
            av[mtd] = *reinterpret_cast<const short8*>(&sm[SV_OFF + (hd * 32 + 16 * mtd + c) * VROW + kb * 32 + 8 * g]);
#pragma unroll
        for (int ntq = 0; ntq < 4; ++ntq)
            bp[ntq] = *reinterpret_cast<const short8*>(&sm[PQ_OFF + hd * 64 * PROW + (16 * ntq + c) * PROW + kb * 32 + 8 * g]);
#pragma unroll
        for (int mtd = 0; mtd < 2; ++mtd)
#pragma unroll
            for (int ntq = 0; ntq < 4; ++ntq)
                pacc[mtd][ntq] = __builtin_amdgcn_mfma_f32_16x16x32_bf16(av[mtd], bp[ntq], pacc[mtd][ntq], 0, 0, 0);
    }

#pragma unroll
    for (int mtd = 0; mtd < 2; ++mtd)
#pragma unroll
        for (int ntq = 0; ntq < 4; ++ntq)
#pragma unroll
            for (int r = 0; r < 4; ++r) {
                const int q = 16 * ntq + c;
                if (q < TT)
                    sm[SQ_OFF + q * SROW + hd * 32 + 16 * mtd + 4 * g + r] = f2b(pacc[mtd][ntq][r]);
            }
    __syncthreads();

    stage_gemm<3>(sm, SQ_OFF, 0, W_out + nHH, b_out + (size_t)n * HH, out + (size_t)n * TT * HH);
}

// ---------------------------------------------------------------------------
extern "C" void kernel_launch(void* const* d_in, const int* in_sizes, int n_in,
                              void* d_out, int out_size, void* d_ws, size_t ws_size,
                              hipStream_t stream)
{
    const float* x     = (const float*)d_in[0];
    const float* adj   = (const float*)d_in[1];
    const int*   ego   = (const int*)d_in[2];
    const float* W1    = (const float*)d_in[3];
    const float* b1    = (const float*)d_in[4];
    const float* W2    = (const float*)d_in[5];
    const float* b2    = (const float*)d_in[6];
    const float* Wq    = (const float*)d_in[7];
    const float* bq    = (const float*)d_in[8];
    const float* Wk    = (const float*)d_in[9];
    const float* bk    = (const float*)d_in[10];
    const float* Wv    = (const float*)d_in[11];
    const float* bv    = (const float*)d_in[12];
    const float* W_in  = (const float*)d_in[13];
    const float* b_in  = (const float*)d_in[14];
    const float* W_out = (const float*)d_in[15];
    const float* b_out = (const float*)d_in[16];
    float* out = (float*)d_out;

    char* ws = (char*)d_ws;
    float*          MF   = (float*)(ws + 0);
    float*          DINV = (float*)(ws + 102400);
    int*            CNT  = (int*)(ws + 204800);
    unsigned short* IDX  = (unsigned short*)(ws + 307200);       // 26,214,400 B
    float*          XW   = (float*)(ws + 26521600);              // 13,107,200 B
    float*          H1   = (float*)(ws + 39628800);              // 13,107,200 B
    float*          EMB  = (float*)(ws + 52736000);              // 13,107,200 B

    hipMemsetAsync(CNT, 0, TT * NN * sizeof(int), stream);
    mf_kernel<<<dim3(100), dim3(256), 0, stream>>>(ego, MF);
    edge_kernel<<<dim3(TT * NN), dim3(128), 0, stream>>>(adj, MF, CNT, IDX);
    dinv_kernel<<<dim3(100), dim3(256), 0, stream>>>(MF, CNT, DINV);
    xw1_kernel<<<dim3(12800), dim3(256), 0, stream>>>(x, W1, DINV, XW);
    agg_kernel<<<dim3(TT * NN), dim3(128), 0, stream>>>(XW, MF, DINV, CNT, IDX, b1, H1, 1);
    xw2_kernel<<<dim3(TT * 16), dim3(128), 0, stream>>>(H1, W2, DINV, XW);
    agg_kernel<<<dim3(TT * NN), dim3(128), 0, stream>>>(XW, MF, DINV, CNT, IDX, b2, EMB, 0);
    node_attn_kernel<<<dim3(NN), dim3(256), 0, stream>>>(EMB, Wq, bq, Wk, bk, Wv, bv,
                                                         W_in, b_in, W_out, b_out, out);
}